// Round 3
// baseline (132.107 us; speedup 1.0000x reference)
//
#include <hip/hip_runtime.h>

using u16 = unsigned short;

// Fixed problem shape (guarded in the launcher; fallback kernel otherwise).
constexpr int Bc = 2, Tc = 8, Fc = 5, Mc = 128, Sc = 128;
constexpr int Np = 65536;         // points per (b,t) slab
constexpr int WPTS = 512;         // points per wave-chunk
constexpr int NCH = Np / WPTS;    // 128 chunks per slab

// Largest x with __fsqrt_rn(x) <= r  (monotone correctly-rounded sqrt =>
// d2 <= T(r)  <=>  __fsqrt_rn(d2) <= r, the reference predicate, bit-exact).
__device__ __forceinline__ float sqrt_ub(float r) {
    float u = __fmul_rn(r, r);
    if (__fsqrt_rn(u) <= r) {
        while (true) {
            float nu = __uint_as_float(__float_as_uint(u) + 1u);
            if (__fsqrt_rn(nu) <= r) u = nu; else break;
        }
    } else {
        while (__fsqrt_rn(u) > r) u = __uint_as_float(__float_as_uint(u) - 1u);
    }
    return u;
}

__device__ __forceinline__ float box_radius(const float* __restrict__ box) {
    const float hl = __fmul_rn(0.5f, box[3]);
    const float hw = __fmul_rn(0.5f, box[4]);
    return __fmul_rn(__fsqrt_rn(__fadd_rn(__fmul_rn(hl, hl), __fmul_rn(hw, hw))), 1.1f);
}

// ---------------- K1: per-chunk hit counts (active boxes only) ----------------
// grid: 512 blocks (bt = blk & 15 for load balance, grp = blk >> 4), 256 thr.
// wave w handles chunk grp*4 + w of slab bt; counts -> ws[bt][chunk][m] (u16).
__global__ __launch_bounds__(256) void k_count(
    const float* __restrict__ points, const float* __restrict__ rois,
    const int* __restrict__ vlen, u16* __restrict__ cnt)
{
    __shared__ float sX[Mc], sY[Mc], sT[Mc];
    __shared__ int sAct[Mc];
    const int bt  = blockIdx.x & 15;
    const int grp = blockIdx.x >> 4;
    const int t = bt & 7;
    const int tid = threadIdx.x;
    if (tid < Mc) {
        const int m = tid;
        const int act = (t == 0) || (vlen[bt * Mc + m] != 0);
        sAct[m] = act;
        if (act) {
            const float* box = rois + (size_t)(bt * Mc + m) * 7;
            sX[m] = box[0]; sY[m] = box[1]; sT[m] = sqrt_ub(box_radius(box));
        }
    }
    __syncthreads();

    const int lane  = tid & 63;
    const int chunk = grp * 4 + (tid >> 6);
    const float* pb = points + (size_t)bt * Np * Fc;
    const int pbase = chunk * WPTS;
    float px[8], py[8];
    #pragma unroll
    for (int k = 0; k < 8; ++k) {
        const size_t idx = (size_t)(pbase + k * 64 + lane);
        px[k] = pb[idx * Fc + 0];
        py[k] = pb[idx * Fc + 1];
    }
    u16* crow = cnt + (size_t)(bt * NCH + chunk) * Mc;
    for (int m = 0; m < Mc; ++m) {
        if (!sAct[m]) continue;
        const float cx = sX[m], cy = sY[m], T = sT[m];
        int c = 0;
        #pragma unroll
        for (int k = 0; k < 8; ++k) {
            const float dx = __fsub_rn(px[k], cx);
            const float dy = __fsub_rn(py[k], cy);
            const float d2 = __fadd_rn(__fmul_rn(dx, dx), __fmul_rn(dy, dy));
            c += (int)__popcll(__ballot(d2 <= T));
        }
        if (lane == 0) crow[m] = (u16)c;
    }
}

// ---------------- K2: prefix-scan counts -> clamped bases; zero tails --------
// wave per (bt, m) row; in-place in ws. grid: 256 blocks x 512 thr.
__global__ __launch_bounds__(512) void k_scan(
    u16* __restrict__ buf, const int* __restrict__ vlen, float* __restrict__ out)
{
    const int row  = blockIdx.x * 8 + (threadIdx.x >> 6);   // 0..2047 == bt*Mc+m
    const int lane = threadIdx.x & 63;
    const int bt = row >> 7, m = row & 127;
    const int t = bt & 7, b = bt >> 3;
    if (t != 0 && vlen[row] == 0) return;                   // fallback row: K4 covers it
    u16* col = buf + (size_t)bt * NCH * Mc + m;
    const int a  = col[(size_t)(2 * lane) * Mc];
    const int b2 = col[(size_t)(2 * lane + 1) * Mc];
    const int s = a + b2;
    int incl = s;
    #pragma unroll
    for (int d = 1; d < 64; d <<= 1) { int v = __shfl_up(incl, d); if (lane >= d) incl += v; }
    const int excl = incl - s;
    const int tot  = __shfl(incl, 63);
    col[(size_t)(2 * lane) * Mc]     = (u16)min(excl, 255);
    col[(size_t)(2 * lane + 1) * Mc] = (u16)min(excl + a, 255);
    const int fill = min(tot, Sc);
    float* ob = out + (size_t)((b * Mc + m) * Tc + t) * (Sc * Fc);
    for (int i = fill * Fc + lane; i < Sc * Fc; i += 64) ob[i] = 0.0f;
}

// ---------------- K3: emit winners (chunks with base < S only) ---------------
// grid: 2048 blocks (bt*NCH+chunk) x 256 thr; wave = 32-box quarter, no barrier.
__global__ __launch_bounds__(256) void k_emit(
    const float* __restrict__ points, const float* __restrict__ rois,
    const u16* __restrict__ base, float* __restrict__ out)
{
    const int chunk = blockIdx.x & (NCH - 1);
    const int bt = blockIdx.x >> 7;
    const int t = bt & 7, b = bt >> 3;
    const int lane = threadIdx.x & 63;
    const int wq = threadIdx.x >> 6;
    const u16* brow = base + (size_t)(bt * NCH + chunk) * Mc;

    const int mj = wq * 32 + (lane & 31);
    const int bm = brow[mj];
    const bool needy = (bm < Sc) && (lane < 32);
    const unsigned long long nb = __ballot(needy);
    if (nb == 0) return;
    const unsigned qmask = (unsigned)nb;

    float rcx = 0.0f, rcy = 0.0f, rT = 0.0f;
    if (needy) {
        const float* box = rois + (size_t)(bt * Mc + mj) * 7;
        rcx = box[0]; rcy = box[1]; rT = sqrt_ub(box_radius(box));
    }

    const float* pb = points + (size_t)bt * Np * Fc;
    const int pbase = chunk * WPTS;
    float px[8], py[8];
    #pragma unroll
    for (int k = 0; k < 8; ++k) {
        const size_t idx = (size_t)(pbase + k * 64 + lane);
        px[k] = pb[idx * Fc + 0];
        py[k] = pb[idx * Fc + 1];
    }
    const unsigned long long lt = (1ull << lane) - 1ull;

    for (int j = 0; j < 32; ++j) {
        if (!((qmask >> j) & 1u)) continue;
        const float cx = __shfl(rcx, j), cy = __shfl(rcy, j), T = __shfl(rT, j);
        int sb = __shfl(bm, j);
        const int mg = wq * 32 + j;
        float* orow = out + (size_t)((b * Mc + mg) * Tc + t) * (Sc * Fc);
        #pragma unroll
        for (int k = 0; k < 8; ++k) {
            const float dx = __fsub_rn(px[k], cx);
            const float dy = __fsub_rn(py[k], cy);
            const float d2 = __fadd_rn(__fmul_rn(dx, dx), __fmul_rn(dy, dy));
            const bool inside = (d2 <= T);
            const unsigned long long bal = __ballot(inside);
            if (inside) {
                const int slot = sb + (int)__popcll(bal & lt);
                if (slot < Sc) {
                    const size_t idx = (size_t)(pbase + k * 64 + lane);
                    const float* p = pb + idx * Fc;
                    const float f2 = p[2], f3 = p[3], f4 = p[4];
                    float* o = orow + (size_t)slot * Fc;
                    o[0] = px[k]; o[1] = py[k]; o[2] = f2; o[3] = f3; o[4] = f4;
                }
            }
            sb += (int)__popcll(bal);
        }
    }
}

// ---------------- K4: copy frame-0 rows into fallback rows -------------------
__global__ __launch_bounds__(256) void k_mirror(
    const int* __restrict__ vlen, float* __restrict__ out)
{
    const int w = blockIdx.x * 4 + (threadIdx.x >> 6);
    if (w >= Bc * (Tc - 1) * Mc) return;
    const int lane = threadIdx.x & 63;
    const int b  = w / ((Tc - 1) * Mc);
    const int r  = w % ((Tc - 1) * Mc);
    const int tp = r / Mc + 1;
    const int m  = r % Mc;
    if (vlen[(b * Tc + tp) * Mc + m] != 0) return;
    const float* src = out + (size_t)((b * Mc + m) * Tc + 0) * (Sc * Fc);
    float* dst       = out + (size_t)((b * Mc + m) * Tc + tp) * (Sc * Fc);
    for (int i = lane; i < Sc * Fc; i += 64) dst[i] = src[i];
}

// ---------------- fallback: R2 single-kernel path (shape-generic) ------------
__global__ __launch_bounds__(1024) void vox_pool(
    const float* __restrict__ points, const float* __restrict__ rois,
    const int* __restrict__ valid_length, float* __restrict__ out,
    int N, int M, int S)
{
    const int blk = blockIdx.x;
    const int m = blk % M;
    const int t = (blk / M) % Tc;
    const int b = blk / (M * Tc);
    int t_eff = t;
    if (t != 0 && valid_length[(b * Tc + t) * M + m] == 0) t_eff = 0;
    const float* box = rois + (size_t)((b * Tc + t_eff) * M + m) * 7;
    const float cx = box[0], cy = box[1];
    const float r = box_radius(box);
    const float* pts = points + (size_t)(b * Tc + t_eff) * N * Fc;
    float* o = out + ((size_t)(b * M + m) * Tc + t) * (size_t)S * Fc;
    __shared__ int wcnt[16];
    const int tid = threadIdx.x, lane = tid & 63, wav = tid >> 6;
    const int nthreads = blockDim.x, nwaves = nthreads >> 6;
    int cnt = 0;
    for (int basei = 0; basei < N; basei += nthreads) {
        const int idx = basei + tid;
        bool inside = false;
        if (idx < N) {
            const float dx = __fsub_rn(pts[(size_t)idx * Fc + 0], cx);
            const float dy = __fsub_rn(pts[(size_t)idx * Fc + 1], cy);
            const float d2 = __fadd_rn(__fmul_rn(dx, dx), __fmul_rn(dy, dy));
            inside = (__fsqrt_rn(d2) <= r);
        }
        const unsigned long long bal = __ballot(inside);
        if (lane == 0) wcnt[wav] = __popcll(bal);
        __syncthreads();
        int wave_off = 0, block_tot = 0;
        for (int w = 0; w < nwaves; ++w) {
            const int c = wcnt[w];
            if (w < wav) wave_off += c;
            block_tot += c;
        }
        if (inside) {
            const int slot = cnt + wave_off + (int)__popcll(bal & ((1ull << lane) - 1ull));
            if (slot < S)
                for (int f = 0; f < Fc; ++f)
                    o[(size_t)slot * Fc + f] = pts[(size_t)idx * Fc + f];
        }
        cnt += block_tot;
        __syncthreads();
        if (cnt >= S) break;
    }
    const int filled = cnt < S ? cnt : S;
    for (int s = filled + tid; s < S; s += nthreads)
        for (int f = 0; f < Fc; ++f)
            o[(size_t)s * Fc + f] = 0.0f;
}

extern "C" void kernel_launch(void* const* d_in, const int* in_sizes, int n_in,
                              void* d_out, int out_size, void* d_ws, size_t ws_size,
                              hipStream_t stream) {
    const float* points = (const float*)d_in[0];
    const float* rois   = (const float*)d_in[1];
    const int*   vlen   = (const int*)d_in[2];
    float* out = (float*)d_out;

    const bool fixed =
        in_sizes[0] == Bc * Tc * Np * Fc &&
        in_sizes[1] == Bc * Tc * Mc * 7 &&
        in_sizes[2] == Bc * Tc * Mc &&
        out_size    == Bc * Mc * Tc * Sc * Fc &&
        ws_size     >= (size_t)(Bc * Tc) * NCH * Mc * sizeof(u16);

    if (fixed) {
        u16* cnt = (u16*)d_ws;
        k_count <<<dim3(Bc * Tc * (NCH / 4)), 256, 0, stream>>>(points, rois, vlen, cnt);
        k_scan  <<<dim3(Bc * Tc * Mc / 8),    512, 0, stream>>>(cnt, vlen, out);
        k_emit  <<<dim3(Bc * Tc * NCH),       256, 0, stream>>>(points, rois, cnt, out);
        k_mirror<<<dim3((Bc * (Tc - 1) * Mc + 3) / 4), 256, 0, stream>>>(vlen, out);
    } else {
        const int N = in_sizes[0] / (Bc * Tc * Fc);
        const int M = in_sizes[2] / (Bc * Tc);
        const int S = out_size / (Bc * M * Tc * Fc);
        vox_pool<<<dim3(Bc * Tc * M), 1024, 0, stream>>>(points, rois, vlen, out, N, M, S);
    }
}

// Round 5
// 123.512 us; speedup vs baseline: 1.0696x; 1.0696x over previous
//
#include <hip/hip_runtime.h>

using u16 = unsigned short;

// Fixed problem shape (guarded in the launcher; generic fallback otherwise).
constexpr int Bc = 2, Tc = 8, Fc = 5, Mc = 128, Sc = 128;
constexpr int Np = 65536;         // points per (b,t) slab
constexpr int WPTS = 512;         // points per chunk
constexpr int NCH = Np / WPTS;    // 128 chunks per slab
constexpr int NBT = Bc * Tc;      // 16 slabs

// Largest x with __fsqrt_rn(x) <= r (monotone correctly-rounded sqrt =>
// d2 <= sqrt_ub(r)  <=>  __fsqrt_rn(d2) <= r : the reference predicate, bit-exact).
__device__ __forceinline__ float sqrt_ub(float r) {
    float u = __fmul_rn(r, r);
    if (__fsqrt_rn(u) <= r) {
        while (true) {
            float nu = __uint_as_float(__float_as_uint(u) + 1u);
            if (__fsqrt_rn(nu) <= r) u = nu; else break;
        }
    } else {
        while (__fsqrt_rn(u) > r) u = __uint_as_float(__float_as_uint(u) - 1u);
    }
    return u;
}

__device__ __forceinline__ float box_radius(const float* __restrict__ box) {
    const float hl = __fmul_rn(0.5f, box[3]);
    const float hw = __fmul_rn(0.5f, box[4]);
    return __fmul_rn(__fsqrt_rn(__fadd_rn(__fmul_rn(hl, hl), __fmul_rn(hw, hw))), 1.1f);
}

// ---------------- K0: pack xy -> dense float2 (coalesced everywhere after) ---
__global__ __launch_bounds__(256) void k_pack(
    const float* __restrict__ pts, float2* __restrict__ packed)
{
    const size_t i = (size_t)blockIdx.x * 256 + threadIdx.x;  // < NBT*Np
    const float x = pts[i * Fc + 0];
    const float y = pts[i * Fc + 1];
    packed[i] = make_float2(x, y);
}

// ---------------- K1: per-chunk hit counts, ballot-style ---------------------
// grid: 512 blocks (bt = blk & 15, grp = blk >> 4) x 256 thr; wave = 1 chunk.
__global__ __launch_bounds__(256) void k_count(
    const float2* __restrict__ packed, const float* __restrict__ rois,
    u16* __restrict__ cnt)
{
    __shared__ float sX[Mc], sY[Mc], sT[Mc];
    const int bt  = blockIdx.x & (NBT - 1);
    const int grp = blockIdx.x >> 4;
    const int tid = threadIdx.x;
    if (tid < Mc) {
        const float* box = rois + (size_t)(bt * Mc + tid) * 7;
        sX[tid] = box[0]; sY[tid] = box[1]; sT[tid] = sqrt_ub(box_radius(box));
    }
    __syncthreads();

    const int lane  = tid & 63;
    const int chunk = grp * 4 + (tid >> 6);
    const float2* pc = packed + (size_t)bt * Np + (size_t)chunk * WPTS;
    float px[8], py[8];
    #pragma unroll
    for (int k = 0; k < 8; ++k) {
        const float2 q = pc[k * 64 + lane];
        px[k] = q.x; py[k] = q.y;
    }
    u16* crow = cnt + (size_t)(bt * NCH + chunk) * Mc;
    for (int m = 0; m < Mc; ++m) {
        const float cx = sX[m], cy = sY[m], T = sT[m];
        int c = 0;
        #pragma unroll
        for (int k = 0; k < 8; ++k) {
            const float dx = __fsub_rn(px[k], cx);
            const float dy = __fsub_rn(py[k], cy);
            const float d2 = __fadd_rn(__fmul_rn(dx, dx), __fmul_rn(dy, dy));
            c += (int)__popcll(__ballot(d2 <= T));
        }
        if (lane == 0) crow[m] = (u16)c;
    }
}

// ---------------- K2: prefix-scan counts -> clamped bases; zero all tails ----
// wave per (bt, m) row; in-place in ws. grid: 256 blocks x 512 thr.
__global__ __launch_bounds__(512) void k_scan(
    u16* __restrict__ buf, float* __restrict__ out)
{
    const int row  = blockIdx.x * 8 + (threadIdx.x >> 6);   // bt*Mc + m
    const int lane = threadIdx.x & 63;
    const int bt = row >> 7, m = row & (Mc - 1);
    const int t = bt & 7, b = bt >> 3;
    u16* col = buf + (size_t)bt * NCH * Mc + m;
    const int a  = col[(size_t)(2 * lane) * Mc];
    const int a2 = col[(size_t)(2 * lane + 1) * Mc];
    const int s = a + a2;
    int incl = s;
    #pragma unroll
    for (int d = 1; d < 64; d <<= 1) { int v = __shfl_up(incl, d); if (lane >= d) incl += v; }
    const int excl = incl - s;
    const int tot  = __shfl(incl, 63);
    col[(size_t)(2 * lane) * Mc]     = (u16)min(excl, 255);
    col[(size_t)(2 * lane + 1) * Mc] = (u16)min(excl + a, 255);
    const int fill = min(tot, Sc);
    float* ob = out + (size_t)((b * Mc + m) * Tc + t) * (Sc * Fc);
    for (int i = fill * Fc + lane; i < Sc * Fc; i += 64) ob[i] = 0.0f;
}

// ---------------- K3': emit, lane-per-box, LDS-staged chunk ------------------
// grid: 2048 blocks (bt*NCH + chunk) x 128 thr (thread == box). No cross-lane
// ops in the scan loop: each lane runs a private slot counter from its base.
__global__ __launch_bounds__(128) void k_emit2(
    const float2* __restrict__ packed, const float* __restrict__ points,
    const float* __restrict__ rois, const u16* __restrict__ base,
    float* __restrict__ out)
{
    const int chunk = blockIdx.x & (NCH - 1);
    const int bt = blockIdx.x >> 7;
    const int t = bt & 7, b = bt >> 3;
    const int tid = threadIdx.x;                 // box index m

    __shared__ float2 sp[WPTS];
    __shared__ unsigned long long sNb[2];

    const int bm = base[(size_t)(bt * NCH + chunk) * Mc + tid];
    const bool needy = (bm < Sc);
    // UNIFORM ballot (all lanes execute the same call — no divergence).
    const unsigned long long wb = __ballot(needy);
    if ((tid & 63) == 0) sNb[tid >> 6] = wb;
    __syncthreads();
    if ((sNb[0] | sNb[1]) == 0ull) return;       // block-uniform exit

    // stage chunk xy into LDS (coalesced float2)
    const float2* pc = packed + (size_t)bt * Np + (size_t)chunk * WPTS;
    for (int i = tid; i < WPTS; i += 128) sp[i] = pc[i];
    __syncthreads();

    if (wb == 0ull) return;                      // wave-uniform: this wave idle

    const float* box = rois + (size_t)(bt * Mc + tid) * 7;
    const float cx = box[0], cy = box[1];
    const float T = sqrt_ub(box_radius(box));
    float* orow = out + (size_t)((b * Mc + tid) * Tc + t) * (Sc * Fc);
    const float* pb = points + ((size_t)bt * Np + (size_t)chunk * WPTS) * Fc;

    int slot = bm;
    #pragma unroll 4
    for (int p = 0; p < WPTS; ++p) {
        const float2 q = sp[p];                  // same-address broadcast: free
        const float dx = __fsub_rn(q.x, cx);
        const float dy = __fsub_rn(q.y, cy);
        const float d2 = __fadd_rn(__fmul_rn(dx, dx), __fmul_rn(dy, dy));
        if (d2 <= T) {
            if (slot < Sc) {
                const float* src = pb + (size_t)p * Fc;
                float* o = orow + (size_t)slot * Fc;
                o[0] = q.x; o[1] = q.y; o[2] = src[2]; o[3] = src[3]; o[4] = src[4];
            }
            ++slot;
        }
    }
}

// ---------------- K4: copy frame-0 rows into fallback rows -------------------
__global__ __launch_bounds__(256) void k_mirror(
    const int* __restrict__ vlen, float* __restrict__ out)
{
    const int w = blockIdx.x * 4 + (threadIdx.x >> 6);
    if (w >= Bc * (Tc - 1) * Mc) return;
    const int lane = threadIdx.x & 63;
    const int b  = w / ((Tc - 1) * Mc);
    const int r  = w % ((Tc - 1) * Mc);
    const int tp = r / Mc + 1;
    const int m  = r % Mc;
    if (vlen[(b * Tc + tp) * Mc + m] != 0) return;
    const float* src = out + (size_t)((b * Mc + m) * Tc + 0) * (Sc * Fc);
    float* dst       = out + (size_t)((b * Mc + m) * Tc + tp) * (Sc * Fc);
    for (int i = lane; i < Sc * Fc; i += 64) dst[i] = src[i];
}

// ---------------- fallback: R2 single-kernel path (shape-generic) ------------
__global__ __launch_bounds__(1024) void vox_pool(
    const float* __restrict__ points, const float* __restrict__ rois,
    const int* __restrict__ valid_length, float* __restrict__ out,
    int N, int M, int S)
{
    const int blk = blockIdx.x;
    const int m = blk % M;
    const int t = (blk / M) % Tc;
    const int b = blk / (M * Tc);
    int t_eff = t;
    if (t != 0 && valid_length[(b * Tc + t) * M + m] == 0) t_eff = 0;
    const float* box = rois + (size_t)((b * Tc + t_eff) * M + m) * 7;
    const float cx = box[0], cy = box[1];
    const float r = box_radius(box);
    const float* pts = points + (size_t)(b * Tc + t_eff) * N * Fc;
    float* o = out + ((size_t)(b * M + m) * Tc + t) * (size_t)S * Fc;
    __shared__ int wcnt[16];
    const int tid = threadIdx.x, lane = tid & 63, wav = tid >> 6;
    const int nthreads = blockDim.x, nwaves = nthreads >> 6;
    int cnt = 0;
    for (int basei = 0; basei < N; basei += nthreads) {
        const int idx = basei + tid;
        bool inside = false;
        if (idx < N) {
            const float dx = __fsub_rn(pts[(size_t)idx * Fc + 0], cx);
            const float dy = __fsub_rn(pts[(size_t)idx * Fc + 1], cy);
            const float d2 = __fadd_rn(__fmul_rn(dx, dx), __fmul_rn(dy, dy));
            inside = (__fsqrt_rn(d2) <= r);
        }
        const unsigned long long bal = __ballot(inside);
        if (lane == 0) wcnt[wav] = __popcll(bal);
        __syncthreads();
        int wave_off = 0, block_tot = 0;
        for (int w = 0; w < nwaves; ++w) {
            const int c = wcnt[w];
            if (w < wav) wave_off += c;
            block_tot += c;
        }
        if (inside) {
            const int slot = cnt + wave_off + (int)__popcll(bal & ((1ull << lane) - 1ull));
            if (slot < S)
                for (int f = 0; f < Fc; ++f)
                    o[(size_t)slot * Fc + f] = pts[(size_t)idx * Fc + f];
        }
        cnt += block_tot;
        __syncthreads();
        if (cnt >= S) break;
    }
    const int filled = cnt < S ? cnt : S;
    for (int s = filled + tid; s < S; s += nthreads)
        for (int f = 0; f < Fc; ++f)
            o[(size_t)s * Fc + f] = 0.0f;
}

extern "C" void kernel_launch(void* const* d_in, const int* in_sizes, int n_in,
                              void* d_out, int out_size, void* d_ws, size_t ws_size,
                              hipStream_t stream) {
    const float* points = (const float*)d_in[0];
    const float* rois   = (const float*)d_in[1];
    const int*   vlen   = (const int*)d_in[2];
    float* out = (float*)d_out;

    const size_t packed_bytes = (size_t)NBT * Np * sizeof(float2);    // 8 MiB
    const size_t cnt_bytes    = (size_t)NBT * NCH * Mc * sizeof(u16); // 512 KiB

    const bool fixed =
        in_sizes[0] == Bc * Tc * Np * Fc &&
        in_sizes[1] == Bc * Tc * Mc * 7 &&
        in_sizes[2] == Bc * Tc * Mc &&
        out_size    == Bc * Mc * Tc * Sc * Fc &&
        ws_size     >= packed_bytes + cnt_bytes;

    if (fixed) {
        float2* packed = (float2*)d_ws;
        u16*    cnt    = (u16*)((char*)d_ws + packed_bytes);
        k_pack  <<<dim3(NBT * Np / 256),     256, 0, stream>>>(points, packed);
        k_count <<<dim3(NBT * (NCH / 4)),    256, 0, stream>>>(packed, rois, cnt);
        k_scan  <<<dim3(NBT * Mc / 8),       512, 0, stream>>>(cnt, out);
        k_emit2 <<<dim3(NBT * NCH),          128, 0, stream>>>(packed, points, rois, cnt, out);
        k_mirror<<<dim3((Bc * (Tc - 1) * Mc + 3) / 4), 256, 0, stream>>>(vlen, out);
    } else {
        const int N = in_sizes[0] / (Bc * Tc * Fc);
        const int M = in_sizes[2] / (Bc * Tc);
        const int S = out_size / (Bc * M * Tc * Fc);
        vox_pool<<<dim3(Bc * Tc * M), 1024, 0, stream>>>(points, rois, vlen, out, N, M, S);
    }
}

// Round 6
// 111.679 us; speedup vs baseline: 1.1829x; 1.1060x over previous
//
#include <hip/hip_runtime.h>

using u16 = unsigned short;
using u32 = unsigned int;
using u64 = unsigned long long;

// Fixed problem shape (guarded in the launcher; generic fallback otherwise).
constexpr int Bc = 2, Tc = 8, Fc = 5, Mc = 128, Sc = 128;
constexpr int Np = 65536;         // points per (b,t) slab
constexpr int WPTS = 512;         // points per chunk
constexpr int NCH = Np / WPTS;    // 128 chunks per slab
constexpr int NBT = Bc * Tc;      // 16 slabs
constexpr int MAX_ITEMS = NBT * Mc * NCH;  // worst case 262144

// Largest x with __fsqrt_rn(x) <= r (monotone correctly-rounded sqrt =>
// d2 <= sqrt_ub(r)  <=>  __fsqrt_rn(d2) <= r : the reference predicate, bit-exact).
__device__ __forceinline__ float sqrt_ub(float r) {
    float u = __fmul_rn(r, r);
    if (__fsqrt_rn(u) <= r) {
        while (true) {
            float nu = __uint_as_float(__float_as_uint(u) + 1u);
            if (__fsqrt_rn(nu) <= r) u = nu; else break;
        }
    } else {
        while (__fsqrt_rn(u) > r) u = __uint_as_float(__float_as_uint(u) - 1u);
    }
    return u;
}

__device__ __forceinline__ float box_radius(const float* __restrict__ box) {
    const float hl = __fmul_rn(0.5f, box[3]);
    const float hw = __fmul_rn(0.5f, box[4]);
    return __fmul_rn(__fsqrt_rn(__fadd_rn(__fmul_rn(hl, hl), __fmul_rn(hw, hw))), 1.1f);
}

// ---------------- K0: pack xy -> dense float2; zero the item counter ---------
__global__ __launch_bounds__(256) void k_pack(
    const float* __restrict__ pts, float2* __restrict__ packed,
    int* __restrict__ counter)
{
    const size_t i = (size_t)blockIdx.x * 256 + threadIdx.x;  // < NBT*Np
    if (i == 0) counter[0] = 0;
    const float x = pts[i * Fc + 0];
    const float y = pts[i * Fc + 1];
    packed[i] = make_float2(x, y);
}

// ---------------- K1: per-chunk hit counts -> cnt[bt][m][chunk] --------------
// grid: 512 blocks (bt = blk & 15, grp = blk >> 4) x 256 thr; wave = 1 chunk.
__global__ __launch_bounds__(256) void k_count(
    const float2* __restrict__ packed, const float* __restrict__ rois,
    u16* __restrict__ cnt)
{
    __shared__ float sX[Mc], sY[Mc], sT[Mc];
    const int bt  = blockIdx.x & (NBT - 1);
    const int grp = blockIdx.x >> 4;
    const int tid = threadIdx.x;
    if (tid < Mc) {
        const float* box = rois + (size_t)(bt * Mc + tid) * 7;
        sX[tid] = box[0]; sY[tid] = box[1]; sT[tid] = sqrt_ub(box_radius(box));
    }
    __syncthreads();

    const int lane  = tid & 63;
    const int chunk = grp * 4 + (tid >> 6);
    const float2* pc = packed + (size_t)bt * Np + (size_t)chunk * WPTS;
    float px[8], py[8];
    #pragma unroll
    for (int k = 0; k < 8; ++k) {
        const float2 q = pc[k * 64 + lane];
        px[k] = q.x; py[k] = q.y;
    }
    for (int m = 0; m < Mc; ++m) {
        const float cx = sX[m], cy = sY[m], T = sT[m];
        int c = 0;
        #pragma unroll
        for (int k = 0; k < 8; ++k) {
            const float dx = __fsub_rn(px[k], cx);
            const float dy = __fsub_rn(py[k], cy);
            const float d2 = __fadd_rn(__fmul_rn(dx, dx), __fmul_rn(dy, dy));
            c += (int)__popcll(__ballot(d2 <= T));
        }
        if (lane == 0) cnt[((size_t)(bt * Mc + m)) * NCH + chunk] = (u16)c;
    }
}

// ---------------- K2: scan rows, build worklist, zero output tails -----------
// wave per (bt, m) row; coalesced u32 reads (2 counts per lane).
__global__ __launch_bounds__(512) void k_scan(
    const u16* __restrict__ cnt, u32* __restrict__ items,
    int* __restrict__ counter, float* __restrict__ out)
{
    const int row  = blockIdx.x * 8 + (threadIdx.x >> 6);   // bt*Mc + m
    const int lane = threadIdx.x & 63;
    const int bt = row >> 7, m = row & (Mc - 1);
    const int t = bt & 7, b = bt >> 3;

    const u32 two = ((const u32*)(cnt + (size_t)row * NCH))[lane];
    const int a  = (int)(two & 0xFFFFu);
    const int a2 = (int)(two >> 16);
    const int s = a + a2;
    int incl = s;
    #pragma unroll
    for (int d = 1; d < 64; d <<= 1) { int v = __shfl_up(incl, d); if (lane >= d) incl += v; }
    const int excl = incl - s;            // base of chunk 2*lane (exact if <128)
    const int tot  = __shfl(incl, 63);
    const int base2 = excl + a;           // base of chunk 2*lane+1

    const bool i1 = (a  > 0) && (excl  < Sc);
    const bool i2 = (a2 > 0) && (base2 < Sc);
    const u64 b1 = __ballot(i1);
    const u64 b2 = __ballot(i2);
    const int n1 = (int)__popcll(b1);
    const int total = n1 + (int)__popcll(b2);
    if (total > 0) {
        int pos0 = 0;
        if (lane == 0) pos0 = atomicAdd(counter, total);
        pos0 = __shfl(pos0, 0);
        const u64 lt = (1ull << lane) - 1ull;
        // item = bt[4] | chunk[7] | m[7] | base[7]
        if (i1) items[pos0 + (int)__popcll(b1 & lt)] =
            ((u32)bt << 21) | ((u32)(2 * lane) << 14) | ((u32)m << 7) | (u32)excl;
        if (i2) items[pos0 + n1 + (int)__popcll(b2 & lt)] =
            ((u32)bt << 21) | ((u32)(2 * lane + 1) << 14) | ((u32)m << 7) | (u32)base2;
    }

    // zero the output tail [min(tot,S), S)
    const int fill = min(tot, Sc);
    float* ob = out + (size_t)((b * Mc + m) * Tc + t) * (Sc * Fc);
    for (int i = fill * Fc + lane; i < Sc * Fc; i += 64) ob[i] = 0.0f;
}

// ---------------- K3: emit — grid-stride waves over worklist items -----------
__global__ __launch_bounds__(256) void k_emit3(
    const float2* __restrict__ packed, const float* __restrict__ points,
    const float* __restrict__ rois, const u32* __restrict__ items,
    const int* __restrict__ counter, float* __restrict__ out)
{
    const int n = counter[0];
    const int lane = threadIdx.x & 63;
    const int wid = (int)((blockIdx.x * blockDim.x + threadIdx.x) >> 6);
    const int nw  = (int)((gridDim.x * blockDim.x) >> 6);
    const u64 lt = (1ull << lane) - 1ull;

    for (int i = wid; i < n; i += nw) {
        const u32 it = items[i];
        const int base  = (int)(it & 127u);
        const int m     = (int)((it >> 7) & 127u);
        const int chunk = (int)((it >> 14) & 127u);
        const int bt    = (int)(it >> 21);
        const int t = bt & 7, b = bt >> 3;

        const float* box = rois + (size_t)(bt * Mc + m) * 7;
        const float cx = box[0], cy = box[1];
        const float T = sqrt_ub(box_radius(box));

        const float2* pc = packed + (size_t)bt * Np + (size_t)chunk * WPTS;
        const float* pslab = points + ((size_t)bt * Np + (size_t)chunk * WPTS) * Fc;
        float* orow = out + (size_t)((b * Mc + m) * Tc + t) * (Sc * Fc);

        int sb = base;
        #pragma unroll
        for (int g = 0; g < 8; ++g) {
            const float2 q = pc[g * 64 + lane];
            const float dx = __fsub_rn(q.x, cx);
            const float dy = __fsub_rn(q.y, cy);
            const float d2 = __fadd_rn(__fmul_rn(dx, dx), __fmul_rn(dy, dy));
            const bool inside = (d2 <= T);
            const u64 bal = __ballot(inside);
            if (inside) {
                const int slot = sb + (int)__popcll(bal & lt);
                if (slot < Sc) {
                    const float* src = pslab + (size_t)(g * 64 + lane) * Fc;
                    float* o = orow + (size_t)slot * Fc;
                    o[0] = q.x; o[1] = q.y; o[2] = src[2]; o[3] = src[3]; o[4] = src[4];
                }
            }
            sb += (int)__popcll(bal);
        }
    }
}

// ---------------- K4: copy frame-0 rows into fallback rows -------------------
__global__ __launch_bounds__(256) void k_mirror(
    const int* __restrict__ vlen, float* __restrict__ out)
{
    const int w = blockIdx.x * 4 + (threadIdx.x >> 6);
    if (w >= Bc * (Tc - 1) * Mc) return;
    const int lane = threadIdx.x & 63;
    const int b  = w / ((Tc - 1) * Mc);
    const int r  = w % ((Tc - 1) * Mc);
    const int tp = r / Mc + 1;
    const int m  = r % Mc;
    if (vlen[(b * Tc + tp) * Mc + m] != 0) return;
    const float* src = out + (size_t)((b * Mc + m) * Tc + 0) * (Sc * Fc);
    float* dst       = out + (size_t)((b * Mc + m) * Tc + tp) * (Sc * Fc);
    for (int i = lane; i < Sc * Fc; i += 64) dst[i] = src[i];
}

// ---------------- fallback: R2 single-kernel path (shape-generic) ------------
__global__ __launch_bounds__(1024) void vox_pool(
    const float* __restrict__ points, const float* __restrict__ rois,
    const int* __restrict__ valid_length, float* __restrict__ out,
    int N, int M, int S)
{
    const int blk = blockIdx.x;
    const int m = blk % M;
    const int t = (blk / M) % Tc;
    const int b = blk / (M * Tc);
    int t_eff = t;
    if (t != 0 && valid_length[(b * Tc + t) * M + m] == 0) t_eff = 0;
    const float* box = rois + (size_t)((b * Tc + t_eff) * M + m) * 7;
    const float cx = box[0], cy = box[1];
    const float r = box_radius(box);
    const float* pts = points + (size_t)(b * Tc + t_eff) * N * Fc;
    float* o = out + ((size_t)(b * M + m) * Tc + t) * (size_t)S * Fc;
    __shared__ int wcnt[16];
    const int tid = threadIdx.x, lane = tid & 63, wav = tid >> 6;
    const int nthreads = blockDim.x, nwaves = nthreads >> 6;
    int cnt = 0;
    for (int basei = 0; basei < N; basei += nthreads) {
        const int idx = basei + tid;
        bool inside = false;
        if (idx < N) {
            const float dx = __fsub_rn(pts[(size_t)idx * Fc + 0], cx);
            const float dy = __fsub_rn(pts[(size_t)idx * Fc + 1], cy);
            const float d2 = __fadd_rn(__fmul_rn(dx, dx), __fmul_rn(dy, dy));
            inside = (__fsqrt_rn(d2) <= r);
        }
        const unsigned long long bal = __ballot(inside);
        if (lane == 0) wcnt[wav] = __popcll(bal);
        __syncthreads();
        int wave_off = 0, block_tot = 0;
        for (int w = 0; w < nwaves; ++w) {
            const int c = wcnt[w];
            if (w < wav) wave_off += c;
            block_tot += c;
        }
        if (inside) {
            const int slot = cnt + wave_off + (int)__popcll(bal & ((1ull << lane) - 1ull));
            if (slot < S)
                for (int f = 0; f < Fc; ++f)
                    o[(size_t)slot * Fc + f] = pts[(size_t)idx * Fc + f];
        }
        cnt += block_tot;
        __syncthreads();
        if (cnt >= S) break;
    }
    const int filled = cnt < S ? cnt : S;
    for (int s = filled + tid; s < S; s += nthreads)
        for (int f = 0; f < Fc; ++f)
            o[(size_t)s * Fc + f] = 0.0f;
}

extern "C" void kernel_launch(void* const* d_in, const int* in_sizes, int n_in,
                              void* d_out, int out_size, void* d_ws, size_t ws_size,
                              hipStream_t stream) {
    const float* points = (const float*)d_in[0];
    const float* rois   = (const float*)d_in[1];
    const int*   vlen   = (const int*)d_in[2];
    float* out = (float*)d_out;

    const size_t packed_bytes  = (size_t)NBT * Np * sizeof(float2);    // 8 MiB
    const size_t cnt_bytes     = (size_t)NBT * Mc * NCH * sizeof(u16); // 512 KiB
    const size_t counter_bytes = 64;
    const size_t items_bytes   = (size_t)MAX_ITEMS * sizeof(u32);      // 1 MiB

    const bool fixed =
        in_sizes[0] == Bc * Tc * Np * Fc &&
        in_sizes[1] == Bc * Tc * Mc * 7 &&
        in_sizes[2] == Bc * Tc * Mc &&
        out_size    == Bc * Mc * Tc * Sc * Fc &&
        ws_size     >= packed_bytes + cnt_bytes + counter_bytes + items_bytes;

    if (fixed) {
        char* w = (char*)d_ws;
        float2* packed = (float2*)w;                       w += packed_bytes;
        u16*    cnt    = (u16*)w;                          w += cnt_bytes;
        int*    counter= (int*)w;                          w += counter_bytes;
        u32*    items  = (u32*)w;

        k_pack  <<<dim3(NBT * Np / 256),  256, 0, stream>>>(points, packed, counter);
        k_count <<<dim3(NBT * (NCH / 4)), 256, 0, stream>>>(packed, rois, cnt);
        k_scan  <<<dim3(NBT * Mc / 8),    512, 0, stream>>>(cnt, items, counter, out);
        k_emit3 <<<dim3(512),             256, 0, stream>>>(packed, points, rois, items, counter, out);
        k_mirror<<<dim3((Bc * (Tc - 1) * Mc + 3) / 4), 256, 0, stream>>>(vlen, out);
    } else {
        const int N = in_sizes[0] / (Bc * Tc * Fc);
        const int M = in_sizes[2] / (Bc * Tc);
        const int S = out_size / (Bc * M * Tc * Fc);
        vox_pool<<<dim3(Bc * Tc * M), 1024, 0, stream>>>(points, rois, vlen, out, N, M, S);
    }
}

// Round 7
// 68.374 us; speedup vs baseline: 1.9321x; 1.6334x over previous
//
#include <hip/hip_runtime.h>

using u16 = unsigned short;
using u32 = unsigned int;
using u64 = unsigned long long;

// Fixed problem shape (guarded in the launcher; generic fallback otherwise).
constexpr int Bc = 2, Tc = 8, Fc = 5, Mc = 128, Sc = 128;
constexpr int Np = 65536;         // points per (b,t) slab
constexpr int WPTS = 512;         // points per chunk
constexpr int NCH = Np / WPTS;    // 128 chunks per slab
constexpr int NBT = Bc * Tc;      // 16 slabs
constexpr int MAX_ITEMS = NBT * Mc * NCH;  // worst case 262144

// Largest x with __fsqrt_rn(x) <= r (monotone correctly-rounded sqrt =>
// d2 <= sqrt_ub(r)  <=>  __fsqrt_rn(d2) <= r : the reference predicate, bit-exact).
__device__ __forceinline__ float sqrt_ub(float r) {
    float u = __fmul_rn(r, r);
    if (__fsqrt_rn(u) <= r) {
        while (true) {
            float nu = __uint_as_float(__float_as_uint(u) + 1u);
            if (__fsqrt_rn(nu) <= r) u = nu; else break;
        }
    } else {
        while (__fsqrt_rn(u) > r) u = __uint_as_float(__float_as_uint(u) - 1u);
    }
    return u;
}

__device__ __forceinline__ float box_radius(const float* __restrict__ box) {
    const float hl = __fmul_rn(0.5f, box[3]);
    const float hw = __fmul_rn(0.5f, box[4]);
    return __fmul_rn(__fsqrt_rn(__fadd_rn(__fmul_rn(hl, hl), __fmul_rn(hw, hw))), 1.1f);
}

// ---------------- K1: per-chunk hit counts -> cnt[bt][m][chunk] --------------
// grid: 512 blocks (bt = blk & 15, grp = blk >> 4) x 256 thr; wave = 1 chunk.
// Reads xy straight from points via 5-float4-per-4-points coalesced loads.
// Inactive boxes (t!=0 && vlen==0) are skipped: their rows are mirror-overwritten.
__global__ __launch_bounds__(256) void k_count(
    const float* __restrict__ points, const float* __restrict__ rois,
    const int* __restrict__ vlen, u16* __restrict__ cnt,
    int* __restrict__ counter)
{
    if (blockIdx.x == 0 && threadIdx.x == 0) counter[0] = 0;

    __shared__ float sX[Mc], sY[Mc], sT[Mc];
    __shared__ int sAct[Mc];
    const int bt  = blockIdx.x & (NBT - 1);
    const int grp = blockIdx.x >> 4;
    const int t   = bt & 7;
    const int tid = threadIdx.x;
    if (tid < Mc) {
        const int act = (t == 0) || (vlen[bt * Mc + tid] != 0);
        sAct[tid] = act;
        if (act) {
            const float* box = rois + (size_t)(bt * Mc + tid) * 7;
            sX[tid] = box[0]; sY[tid] = box[1]; sT[tid] = sqrt_ub(box_radius(box));
        }
    }
    __syncthreads();

    const int lane  = tid & 63;
    const int chunk = grp * 4 + (tid >> 6);
    const float* pc = points + ((size_t)bt * Np + (size_t)chunk * WPTS) * Fc;

    float px[8], py[8];
    #pragma unroll
    for (int h = 0; h < 2; ++h) {
        // lane handles 4 consecutive points: 4 pts * 5 floats = 5 float4s, coalesced.
        const float4* src = (const float4*)(pc + (size_t)(h * 256 + lane * 4) * Fc);
        const float4 v0 = src[0], v1 = src[1], v2 = src[2], v3 = src[3], v4 = src[4];
        px[4*h+0] = v0.x; py[4*h+0] = v0.y;
        px[4*h+1] = v1.y; py[4*h+1] = v1.z;
        px[4*h+2] = v2.z; py[4*h+2] = v2.w;
        px[4*h+3] = v3.w; py[4*h+3] = v4.x;
    }

    u16* crow = cnt + (size_t)(bt * Mc) * NCH + chunk;
    for (int m = 0; m < Mc; ++m) {
        if (!sAct[m]) continue;                 // wave-uniform branch
        const float cx = sX[m], cy = sY[m], T = sT[m];
        int c = 0;
        #pragma unroll
        for (int k = 0; k < 8; ++k) {
            const float dx = __fsub_rn(px[k], cx);
            const float dy = __fsub_rn(py[k], cy);
            const float d2 = __fadd_rn(__fmul_rn(dx, dx), __fmul_rn(dy, dy));
            c += (int)__popcll(__ballot(d2 <= T));  // order-free: count only
        }
        if (lane == 0) crow[(size_t)m * NCH] = (u16)c;
    }
}

// ---------------- K2: scan active rows, build worklist, zero output tails ----
// wave per (bt, m) row; coalesced u32 reads (2 counts per lane).
__global__ __launch_bounds__(512) void k_scan(
    const u16* __restrict__ cnt, const int* __restrict__ vlen,
    u32* __restrict__ items, int* __restrict__ counter,
    float* __restrict__ out)
{
    const int row  = blockIdx.x * 8 + (threadIdx.x >> 6);   // bt*Mc + m
    const int lane = threadIdx.x & 63;
    const int bt = row >> 7, m = row & (Mc - 1);
    const int t = bt & 7, b = bt >> 3;
    if (t != 0 && vlen[row] == 0) return;       // mirror covers the whole row

    const u32 two = ((const u32*)(cnt + (size_t)row * NCH))[lane];
    const int a  = (int)(two & 0xFFFFu);
    const int a2 = (int)(two >> 16);
    const int s = a + a2;
    int incl = s;
    #pragma unroll
    for (int d = 1; d < 64; d <<= 1) { int v = __shfl_up(incl, d); if (lane >= d) incl += v; }
    const int excl = incl - s;            // base of chunk 2*lane
    const int tot  = __shfl(incl, 63);
    const int base2 = excl + a;           // base of chunk 2*lane+1

    const bool i1 = (a  > 0) && (excl  < Sc);
    const bool i2 = (a2 > 0) && (base2 < Sc);
    const u64 b1 = __ballot(i1);
    const u64 b2 = __ballot(i2);
    const int n1 = (int)__popcll(b1);
    const int total = n1 + (int)__popcll(b2);
    if (total > 0) {
        int pos0 = 0;
        if (lane == 0) pos0 = atomicAdd(counter, total);
        pos0 = __shfl(pos0, 0);
        const u64 lt = (1ull << lane) - 1ull;
        // item = bt[4] | chunk[7] | m[7] | base[7]
        if (i1) items[pos0 + (int)__popcll(b1 & lt)] =
            ((u32)bt << 21) | ((u32)(2 * lane) << 14) | ((u32)m << 7) | (u32)excl;
        if (i2) items[pos0 + n1 + (int)__popcll(b2 & lt)] =
            ((u32)bt << 21) | ((u32)(2 * lane + 1) << 14) | ((u32)m << 7) | (u32)base2;
    }

    // zero the output tail [min(tot,S), S)
    const int fill = min(tot, Sc);
    float* ob = out + (size_t)((b * Mc + m) * Tc + t) * (Sc * Fc);
    for (int i = fill * Fc + lane; i < Sc * Fc; i += 64) ob[i] = 0.0f;
}

// ---------------- K3: emit — LDS-staged chunk, grid-stride waves over items --
// Per item: 10 coalesced float4 loads stage the full 10KB chunk into this
// wave's LDS slice (one latency, no barrier needed: wave-private slice), then
// the ballot loop is pure ALU + LDS (stride-5 dwords: conflict-free) + stores.
__global__ __launch_bounds__(256) void k_emit4(
    const float* __restrict__ points, const float* __restrict__ rois,
    const u32* __restrict__ items, const int* __restrict__ counter,
    float* __restrict__ out)
{
    __shared__ float lds[4][WPTS * Fc];         // 4 waves x 10KB
    const int n = counter[0];
    const int lane = threadIdx.x & 63;
    const int w    = threadIdx.x >> 6;
    const int wid  = blockIdx.x * 4 + w;
    const int nw   = gridDim.x * 4;
    const u64 lt = (1ull << lane) - 1ull;
    float* L = lds[w];

    for (int i = wid; i < n; i += nw) {
        const u32 it = items[i];
        const int base  = (int)(it & 127u);
        const int m     = (int)((it >> 7) & 127u);
        const int chunk = (int)((it >> 14) & 127u);
        const int bt    = (int)(it >> 21);
        const int t = bt & 7, b = bt >> 3;

        // stage chunk (512 pts x 20B) into wave-private LDS, coalesced
        const float4* pc4 = (const float4*)(points + ((size_t)bt * Np + (size_t)chunk * WPTS) * Fc);
        #pragma unroll
        for (int q = 0; q < 10; ++q)
            ((float4*)L)[q * 64 + lane] = pc4[q * 64 + lane];

        const float* box = rois + (size_t)(bt * Mc + m) * 7;
        const float cx = box[0], cy = box[1];
        const float T = sqrt_ub(box_radius(box));
        float* orow = out + (size_t)((b * Mc + m) * Tc + t) * (Sc * Fc);

        int sb = base;
        #pragma unroll
        for (int g = 0; g < 8; ++g) {
            const int p = g * 64 + lane;
            const float qx = L[p * 5 + 0];
            const float qy = L[p * 5 + 1];
            const float dx = __fsub_rn(qx, cx);
            const float dy = __fsub_rn(qy, cy);
            const float d2 = __fadd_rn(__fmul_rn(dx, dx), __fmul_rn(dy, dy));
            const bool inside = (d2 <= T);
            const u64 bal = __ballot(inside);
            if (inside) {
                const int slot = sb + (int)__popcll(bal & lt);
                if (slot < Sc) {
                    float* o = orow + (size_t)slot * Fc;
                    o[0] = qx; o[1] = qy;
                    o[2] = L[p * 5 + 2]; o[3] = L[p * 5 + 3]; o[4] = L[p * 5 + 4];
                }
            }
            sb += (int)__popcll(bal);
        }
    }
}

// ---------------- K4: copy frame-0 rows into fallback rows -------------------
__global__ __launch_bounds__(256) void k_mirror(
    const int* __restrict__ vlen, float* __restrict__ out)
{
    const int w = blockIdx.x * 4 + (threadIdx.x >> 6);
    if (w >= Bc * (Tc - 1) * Mc) return;
    const int lane = threadIdx.x & 63;
    const int b  = w / ((Tc - 1) * Mc);
    const int r  = w % ((Tc - 1) * Mc);
    const int tp = r / Mc + 1;
    const int m  = r % Mc;
    if (vlen[(b * Tc + tp) * Mc + m] != 0) return;
    const float* src = out + (size_t)((b * Mc + m) * Tc + 0) * (Sc * Fc);
    float* dst       = out + (size_t)((b * Mc + m) * Tc + tp) * (Sc * Fc);
    for (int i = lane; i < Sc * Fc; i += 64) dst[i] = src[i];
}

// ---------------- fallback: R2 single-kernel path (shape-generic) ------------
__global__ __launch_bounds__(1024) void vox_pool(
    const float* __restrict__ points, const float* __restrict__ rois,
    const int* __restrict__ valid_length, float* __restrict__ out,
    int N, int M, int S)
{
    const int blk = blockIdx.x;
    const int m = blk % M;
    const int t = (blk / M) % Tc;
    const int b = blk / (M * Tc);
    int t_eff = t;
    if (t != 0 && valid_length[(b * Tc + t) * M + m] == 0) t_eff = 0;
    const float* box = rois + (size_t)((b * Tc + t_eff) * M + m) * 7;
    const float cx = box[0], cy = box[1];
    const float r = box_radius(box);
    const float* pts = points + (size_t)(b * Tc + t_eff) * N * Fc;
    float* o = out + ((size_t)(b * M + m) * Tc + t) * (size_t)S * Fc;
    __shared__ int wcnt[16];
    const int tid = threadIdx.x, lane = tid & 63, wav = tid >> 6;
    const int nthreads = blockDim.x, nwaves = nthreads >> 6;
    int cnt = 0;
    for (int basei = 0; basei < N; basei += nthreads) {
        const int idx = basei + tid;
        bool inside = false;
        if (idx < N) {
            const float dx = __fsub_rn(pts[(size_t)idx * Fc + 0], cx);
            const float dy = __fsub_rn(pts[(size_t)idx * Fc + 1], cy);
            const float d2 = __fadd_rn(__fmul_rn(dx, dx), __fmul_rn(dy, dy));
            inside = (__fsqrt_rn(d2) <= r);
        }
        const unsigned long long bal = __ballot(inside);
        if (lane == 0) wcnt[wav] = __popcll(bal);
        __syncthreads();
        int wave_off = 0, block_tot = 0;
        for (int w = 0; w < nwaves; ++w) {
            const int c = wcnt[w];
            if (w < wav) wave_off += c;
            block_tot += c;
        }
        if (inside) {
            const int slot = cnt + wave_off + (int)__popcll(bal & ((1ull << lane) - 1ull));
            if (slot < S)
                for (int f = 0; f < Fc; ++f)
                    o[(size_t)slot * Fc + f] = pts[(size_t)idx * Fc + f];
        }
        cnt += block_tot;
        __syncthreads();
        if (cnt >= S) break;
    }
    const int filled = cnt < S ? cnt : S;
    for (int s = filled + tid; s < S; s += nthreads)
        for (int f = 0; f < Fc; ++f)
            o[(size_t)s * Fc + f] = 0.0f;
}

extern "C" void kernel_launch(void* const* d_in, const int* in_sizes, int n_in,
                              void* d_out, int out_size, void* d_ws, size_t ws_size,
                              hipStream_t stream) {
    const float* points = (const float*)d_in[0];
    const float* rois   = (const float*)d_in[1];
    const int*   vlen   = (const int*)d_in[2];
    float* out = (float*)d_out;

    const size_t cnt_bytes     = (size_t)NBT * Mc * NCH * sizeof(u16); // 512 KiB
    const size_t counter_bytes = 64;
    const size_t items_bytes   = (size_t)MAX_ITEMS * sizeof(u32);      // 1 MiB

    const bool fixed =
        in_sizes[0] == Bc * Tc * Np * Fc &&
        in_sizes[1] == Bc * Tc * Mc * 7 &&
        in_sizes[2] == Bc * Tc * Mc &&
        out_size    == Bc * Mc * Tc * Sc * Fc &&
        ws_size     >= cnt_bytes + counter_bytes + items_bytes;

    if (fixed) {
        char* w = (char*)d_ws;
        u16* cnt     = (u16*)w;   w += cnt_bytes;
        int* counter = (int*)w;   w += counter_bytes;
        u32* items   = (u32*)w;

        k_count <<<dim3(NBT * (NCH / 4)), 256, 0, stream>>>(points, rois, vlen, cnt, counter);
        k_scan  <<<dim3(NBT * Mc / 8),    512, 0, stream>>>(cnt, vlen, items, counter, out);
        k_emit4 <<<dim3(2048),            256, 0, stream>>>(points, rois, items, counter, out);
        k_mirror<<<dim3((Bc * (Tc - 1) * Mc + 3) / 4), 256, 0, stream>>>(vlen, out);
    } else {
        const int N = in_sizes[0] / (Bc * Tc * Fc);
        const int M = in_sizes[2] / (Bc * Tc);
        const int S = out_size / (Bc * M * Tc * Fc);
        vox_pool<<<dim3(Bc * Tc * M), 1024, 0, stream>>>(points, rois, vlen, out, N, M, S);
    }
}